// Round 3
// baseline (497.614 us; speedup 1.0000x reference)
//
#include <hip/hip_runtime.h>

typedef float  f4   __attribute__((ext_vector_type(4)));
typedef __bf16 bf8_t __attribute__((ext_vector_type(8)));
typedef __bf16 bf4_t __attribute__((ext_vector_type(4)));

// ---------------------------------------------------------------------------
// Positional encodings + combined projection bias.
// P[s,2i]=sin(s*10000^(-2i/d)), P[s,2i+1]=cos(...). Then bc = 2*b_p1 + b_p2.
// ---------------------------------------------------------------------------
__global__ __launch_bounds__(256)
void pos_enc_kernel(float* __restrict__ P1, float* __restrict__ P2,
                    float* __restrict__ P3,
                    const float* __restrict__ bp1, const float* __restrict__ bp2,
                    float* __restrict__ bc) {
    int idx = blockIdx.x * 256 + threadIdx.x;
    const int n1 = 128 * 256, n2 = 128 * 512, n3 = 128 * 1280;
    const int nP = n1 + n2 + n3;
    if (idx >= nP) {
        int j = idx - nP;
        if (j < 32000) bc[j] = 2.f * bp1[j] + bp2[j];
        return;
    }
    float* P; int d, local;
    if (idx < n1)           { P = P1; d = 256;  local = idx; }
    else if (idx < n1 + n2) { P = P2; d = 512;  local = idx - n1; }
    else                    { P = P3; d = 1280; local = idx - n1 - n2; }
    int s = local / d;
    int k = local - s * d;
    int i = k >> 1;
    float expo = (-2.0f * (float)i) / (float)d;
    float ang  = (float)s * powf(10000.0f, expo);
    P[local] = (k & 1) ? cosf(ang) : sinf(ang);
}

// ---------------------------------------------------------------------------
// Generic bf16-MFMA GEMM, LDS double-buffered (2-phase reg-staged pipeline):
//   iter i: issue loads(i+2) | MFMA from buf[cur] | stage regs(i+1)->buf[cur^1]
//   | one barrier. Loads get ~1.5 iters to land before the cvt/ds_write waits.
//   C = [relu]((A[+A2]) @ B + bias) [+ addsrc]   (fp32 in/out, bf16 MFMA)
//   ksplit>1: fp32 partials to C[(batch*ksplit+kz)*M*N], epilogue deferred.
//   xcdmap=1: 1-D grid 1024; all blocks of one k-slice on one XCD.
//   Block 256 thr = 4 waves; tile BM=64 x BN=128, BK=32; wave tile 32x64.
// ---------------------------------------------------------------------------
__global__ __launch_bounds__(256)
void gemm_bf16(const float* __restrict__ A, const float* __restrict__ A2,
               const float* __restrict__ Bm, float* __restrict__ C,
               const float* __restrict__ bias, const float* __restrict__ addsrc,
               int M, int N, int K, int lda, int ldb, int ldc,
               long sA, long sB, long sC, int ksplit, int kchunk, int relu,
               int xcdmap) {
    // pad rows to 40 bf16 = 80 B: 16B-aligned b128 frag reads, <=2-way banks
    __shared__ __align__(16) __bf16 As[2][64][40];
    __shared__ __align__(16) __bf16 Bs[2][128][40];

    const int t = threadIdx.x;
    int bn, bm, bz;
    if (xcdmap) {
        const int lin = blockIdx.x;
        const int xc = lin & 7, j = lin >> 3;
        bz = xc + ((j >> 5) << 3);
        bm = j & 31;
        bn = 0;
    } else {
        bn = blockIdx.x; bm = blockIdx.y; bz = blockIdx.z;
    }
    const int batch = bz / ksplit;
    const int kz    = bz - batch * ksplit;
    const float* Ab = A + (long)batch * sA;
    const float* Bb = Bm + (long)batch * sB;
    const int m0 = bm * 64, n0 = bn * 128;
    const int kb = kz * kchunk;
    const int ke = (kb + kchunk < K) ? (kb + kchunk) : K;
    const int nit = (ke - kb + 31) >> 5;

    const int lane = t & 63;
    const int wv = t >> 6;
    const int wm = wv >> 1, wn = wv & 1;
    const int fr = lane & 15;
    const int fq = (lane >> 4) * 8;

    f4 acc[2][4];
#pragma unroll
    for (int mt = 0; mt < 2; ++mt)
#pragma unroll
        for (int nt = 0; nt < 4; ++nt) acc[mt][nt] = (f4){0.f, 0.f, 0.f, 0.f};

    const int ar = t >> 2;
    const int ak = (t & 3) * 8;
    const int bcx = (t & 31) * 4;
    const int bk = (t >> 5) * 4;

    const bool hasA2 = (A2 != nullptr);
    const bool avalid = (m0 + ar) < M;
    const int arow = avalid ? (m0 + ar) : 0;
    const float* aptr  = Ab + (long)arow * lda + ak;
    const float* a2ptr = hasA2 ? (A2 + (long)batch * sA + (long)arow * lda + ak) : aptr;
    const float* bptr  = Bb + (long)bk * ldb + n0 + bcx;

    // load one 32-K tile into registers (no arithmetic at issue site)
    auto ld = [&](int k0, f4& a0, f4& a1, f4& c0, f4& c1,
                  f4& b0, f4& b1, f4& b2, f4& b3) {
        if (avalid) {
            a0 = *(const f4*)(aptr + k0);
            a1 = *(const f4*)(aptr + k0 + 4);
            if (hasA2) {
                c0 = *(const f4*)(a2ptr + k0);
                c1 = *(const f4*)(a2ptr + k0 + 4);
            }
        } else {
            a0 = (f4){0.f,0.f,0.f,0.f}; a1 = a0;
            if (hasA2) { c0 = a0; c1 = a0; }
        }
        const float* bp = bptr + (long)k0 * ldb;
        b0 = *(const f4*)bp;
        b1 = *(const f4*)(bp + ldb);
        b2 = *(const f4*)(bp + 2 * ldb);
        b3 = *(const f4*)(bp + 3 * ldb);
    };
    // cvt + store one tile into LDS buffer b (vmcnt wait happens here)
    auto stage = [&](int b, f4 a0, f4 a1, f4 c0, f4 c1,
                     f4 b0, f4 b1, f4 b2, f4 b3) {
        if (hasA2) { a0 += c0; a1 += c1; }
        bf8_t av;
        av[0]=(__bf16)a0[0]; av[1]=(__bf16)a0[1]; av[2]=(__bf16)a0[2]; av[3]=(__bf16)a0[3];
        av[4]=(__bf16)a1[0]; av[5]=(__bf16)a1[1]; av[6]=(__bf16)a1[2]; av[7]=(__bf16)a1[3];
        *(bf8_t*)&As[b][ar][ak] = av;
#pragma unroll
        for (int i = 0; i < 4; ++i) {
            bf4_t bv = {(__bf16)b0[i], (__bf16)b1[i], (__bf16)b2[i], (__bf16)b3[i]};
            *(bf4_t*)&Bs[b][bcx + i][bk] = bv;
        }
    };

    f4 sa0, sa1, sc0, sc1, sb0, sb1, sb2, sb3;   // tile to stage next
    f4 pa0, pa1, pc0, pc1, pb0, pb1, pb2, pb3;   // tile being prefetched

    // prologue: tile0 -> buf0; issue tile1
    ld(kb, sa0, sa1, sc0, sc1, sb0, sb1, sb2, sb3);
    stage(0, sa0, sa1, sc0, sc1, sb0, sb1, sb2, sb3);
    if (nit > 1) ld(kb + 32, sa0, sa1, sc0, sc1, sb0, sb1, sb2, sb3);
    __syncthreads();

    int cur = 0;
#pragma unroll 2
    for (int i = 0; i < nit; ++i) {
        const bool h2 = (i + 2) < nit;
        if (h2) ld(kb + (i + 2) * 32, pa0, pa1, pc0, pc1, pb0, pb1, pb2, pb3);

        bf8_t af0 = *(const bf8_t*)&As[cur][wm * 32 + fr][fq];
        bf8_t af1 = *(const bf8_t*)&As[cur][wm * 32 + 16 + fr][fq];
#pragma unroll
        for (int nt = 0; nt < 4; ++nt) {
            bf8_t bfv = *(const bf8_t*)&Bs[cur][wn * 64 + nt * 16 + fr][fq];
            acc[0][nt] = __builtin_amdgcn_mfma_f32_16x16x32_bf16(af0, bfv, acc[0][nt], 0, 0, 0);
            acc[1][nt] = __builtin_amdgcn_mfma_f32_16x16x32_bf16(af1, bfv, acc[1][nt], 0, 0, 0);
        }
        if ((i + 1) < nit)
            stage(cur ^ 1, sa0, sa1, sc0, sc1, sb0, sb1, sb2, sb3);
        __syncthreads();
        if (h2) {
            sa0=pa0; sa1=pa1; sc0=pc0; sc1=pc1;
            sb0=pb0; sb1=pb1; sb2=pb2; sb3=pb3;
        }
        cur ^= 1;
    }

    float* Cp; long ldcp;
    const bool fin = (ksplit == 1);
    if (!fin) { Cp = C + (long)(batch * ksplit + kz) * M * N; ldcp = N; }
    else      { Cp = C + (long)batch * sC;                    ldcp = ldc; }

    const int rb = m0 + wm * 32 + (lane >> 4) * 4;
    const int cb_ = n0 + wn * 64 + fr;
#pragma unroll
    for (int mt = 0; mt < 2; ++mt) {
#pragma unroll
        for (int nt = 0; nt < 4; ++nt) {
            const int c = cb_ + nt * 16;
            const float bv = (fin && bias) ? bias[c] : 0.f;
#pragma unroll
            for (int v = 0; v < 4; ++v) {
                const int r = rb + mt * 16 + v;
                if (r < M) {
                    float val = acc[mt][nt][v] + bv;
                    if (fin && relu) val = fmaxf(val, 0.f);
                    if (fin && addsrc) val += addsrc[(long)r * ldcp + c];
                    Cp[(long)r * ldcp + c] = val;
                }
            }
        }
    }
}

// out[idx] = [relu](sum_z part[z*MN+idx] + bias[idx%N]) + addsrc[idx%addmod]
__global__ __launch_bounds__(256)
void reduce_splitk(const float* __restrict__ part, float* __restrict__ outp,
                   const float* __restrict__ bias, const float* __restrict__ addsrc,
                   int MN, int N, int addmod, int ksplit, int relu) {
    int idx = blockIdx.x * 256 + threadIdx.x;
    if (idx >= MN) return;
    float s = 0.f;
    for (int z = 0; z < ksplit; ++z) s += part[(long)z * MN + idx];
    if (bias) s += bias[idx % N];
    if (relu) s = fmaxf(s, 0.f);
    if (addsrc) s += addsrc[idx % addmod];
    outp[idx] = s;
}

// Fused GEMM1 reduce: h1 = relu(sum_z part + b_emb) + Q1, and rs1 = rowsum(h1).
__global__ __launch_bounds__(256)
void reduce_rs_kernel(const float* __restrict__ part, float* __restrict__ h1,
                      const float* __restrict__ bias, const float* __restrict__ Q1,
                      float* __restrict__ rs1, int ksplit) {
    const int t = threadIdx.x;
    const int idx = blockIdx.x * 256 + t;
    float s = 0.f;
    for (int z = 0; z < ksplit; ++z) s += part[(long)z * 262144 + idx];
    s += bias[idx & 127];
    s = fmaxf(s, 0.f);
    s += Q1[idx & 16383];
    h1[idx] = s;
    float r = s;
    for (int off = 32; off > 0; off >>= 1) r += __shfl_down(r, off, 64);
    __shared__ float p[4];
    const int w = t >> 6, lane = t & 63;
    if (lane == 0) p[w] = r;
    __syncthreads();
    if (t < 2) rs1[(blockIdx.x << 1) + t] = p[t * 2] + p[t * 2 + 1];
}

// one wave per row: rs[r] = sum_j h[r*D + j]
__global__ __launch_bounds__(256)
void rowsum_kernel(const float* __restrict__ h, float* __restrict__ rs,
                   int rows, int D) {
    int gw = (blockIdx.x * 256 + threadIdx.x) >> 6;
    int lane = threadIdx.x & 63;
    if (gw >= rows) return;
    const float* p = h + (long)gw * D;
    float s = 0.f;
    for (int j = lane; j < D; j += 64) s += p[j];
    for (int off = 32; off > 0; off >>= 1) s += __shfl_down(s, off, 64);
    if (lane == 0) rs[gw] = s;
}

// ---------------------------------------------------------------------------
extern "C" void kernel_launch(void* const* d_in, const int* in_sizes, int n_in,
                              void* d_out, int out_size, void* d_ws, size_t ws_size,
                              hipStream_t stream) {
    const float* x       = (const float*)d_in[0];
    const float* W_emb   = (const float*)d_in[1];
    const float* b_emb   = (const float*)d_in[2];
    const float* W_pos1  = (const float*)d_in[3];
    const float* b_pos1  = (const float*)d_in[4];
    const float* W_red   = (const float*)d_in[5];
    const float* b_red   = (const float*)d_in[6];
    const float* W_pos2  = (const float*)d_in[7];
    const float* b_pos2  = (const float*)d_in[8];
    const float* W_red2  = (const float*)d_in[9];
    const float* b_red2  = (const float*)d_in[10];
    const float* W_pos3  = (const float*)d_in[11];
    const float* b_pos3  = (const float*)d_in[12];
    const float* W_down2 = (const float*)d_in[13];
    const float* b_down2 = (const float*)d_in[14];
    const float* W_flat  = (const float*)d_in[15];
    const float* b_flat  = (const float*)d_in[16];
    const float* W_d1    = (const float*)d_in[17];
    const float* b_d1    = (const float*)d_in[18];
    const float* W_d2    = (const float*)d_in[19];
    const float* b_d2    = (const float*)d_in[20];
    const float* W_d3    = (const float*)d_in[21];
    const float* b_d3    = (const float*)d_in[22];
    const float* W_p1    = (const float*)d_in[23];
    const float* b_p1    = (const float*)d_in[24];
    const float* W_p2    = (const float*)d_in[25];
    const float* b_p2    = (const float*)d_in[26];
    float* out = (float*)d_out;
    float* ws  = (float*)d_ws;

    size_t o = 0;
    auto alloc = [&](size_t n) { size_t p = o; o += (n + 63) & ~(size_t)63; return p; };
    const size_t oP1 = alloc(128 * 256);
    const size_t oP2 = alloc(128 * 512);
    const size_t oP3 = alloc(128 * 1280);
    const size_t oQ1 = alloc(128 * 128);
    const size_t oQ2 = alloc(128 * 256);
    const size_t oQ3 = alloc(128 * 640);
    const size_t oBC = alloc(32000);
    const size_t oH1 = alloc(2048 * 128);
    const size_t oRS1 = alloc(2048);
    const size_t oRS2 = alloc(2048);
    const size_t oH2 = alloc(2048 * 256);
    const size_t oH3 = alloc(2048 * 640);
    const size_t oH4 = alloc(2048 * 512);
    const size_t oH5 = alloc(16 * 512);
    const size_t oH6 = alloc(16 * 512);
    const size_t oH7 = alloc(16 * 512);
    const size_t oH8 = alloc(16 * 512);
    const size_t oM1 = alloc(16 * 32768);
    const size_t oM2 = alloc(16 * 163840);
    // RegA reused: Q3 partials -> GEMM1 partials (32x262144) -> W_flat partials
    const size_t oRegA = alloc(32u * 262144);
    const size_t oPartQ3 = oRegA, oPartG1 = oRegA, oPartF = oRegA;
    (void)ws_size; (void)in_sizes; (void)n_in; (void)out_size;

    dim3 blk(256);
    auto gemm = [&](const float* A, const float* A2v, const float* B, float* C,
                    const float* bias, const float* addsrc,
                    int M, int N, int K, int lda, int ldb, int ldc,
                    long sA, long sB, long sC, int batch, int ksplit, int kchunk,
                    int relu) {
        dim3 grid(N / 128, (M + 63) / 64, batch * ksplit);
        gemm_bf16<<<grid, blk, 0, stream>>>(A, A2v, B, C, bias, addsrc,
                                            M, N, K, lda, ldb, ldc,
                                            sA, sB, sC, ksplit, kchunk, relu, 0);
    };

    // 1. positional encodings + combined projection bias (fused)
    pos_enc_kernel<<<dim3(1149), blk, 0, stream>>>(ws + oP1, ws + oP2, ws + oP3,
                                                   b_p1, b_p2, ws + oBC);
    // 2-4. pos projections Q = relu(P @ W_pos + b)
    gemm(ws + oP1, nullptr, W_pos1, ws + oQ1, b_pos1, nullptr,
         128, 128, 256, 256, 128, 128, 0, 0, 0, 1, 1, 256, 1);
    gemm(ws + oP2, nullptr, W_pos2, ws + oQ2, b_pos2, nullptr,
         128, 256, 512, 512, 256, 256, 0, 0, 0, 1, 1, 512, 1);
    gemm(ws + oP3, nullptr, W_pos3, ws + oPartQ3, nullptr, nullptr,
         128, 640, 1280, 1280, 640, 640, 0, 0, 0, 1, 4, 320, 0);
    reduce_splitk<<<dim3(320), blk, 0, stream>>>(ws + oPartQ3, ws + oQ3, b_pos3,
                                                 nullptr, 81920, 640, 1, 4, 1);
    // 5. GEMM1: x(2048x32000) @ W_emb, split-K 32, XCD-grouped
    gemm_bf16<<<dim3(1024), blk, 0, stream>>>(x, nullptr, W_emb, ws + oPartG1,
                                              nullptr, nullptr,
                                              2048, 128, 32000, 32000, 128, 128,
                                              0, 0, 0, 32, 1024, 0, 1);
    // 6. h1 = relu(sum + b_emb) + Q1 ; rs1 = rowsum(h1)
    reduce_rs_kernel<<<dim3(1024), blk, 0, stream>>>(ws + oPartG1, ws + oH1, b_emb,
                                                     ws + oQ1, ws + oRS1, 32);
    // 7. M1 = rs1(16x128) @ W_red viewed (128 x 32768)
    gemm(ws + oRS1, nullptr, W_red, ws + oM1, nullptr, nullptr,
         16, 32768, 128, 128, 32768, 32768, 0, 0, 0, 1, 1, 128, 0);
    // 8. h2 = relu(h1[b] @ M1[b] + b_red) + Q2  (batched)
    gemm(ws + oH1, nullptr, ws + oM1, ws + oH2, b_red, ws + oQ2,
         128, 256, 128, 128, 256, 256, 16384, 32768, 32768, 16, 1, 128, 1);
    // 9. rs2
    rowsum_kernel<<<dim3(512), blk, 0, stream>>>(ws + oH2, ws + oRS2, 2048, 256);
    // 10. M2 = rs2(16x128) @ W_red2 viewed (128 x 163840)
    gemm(ws + oRS2, nullptr, W_red2, ws + oM2, nullptr, nullptr,
         16, 163840, 128, 128, 163840, 163840, 0, 0, 0, 1, 1, 128, 0);
    // 11. h3 = relu(h2[b] @ M2[b] + b_red2) + Q3  (batched)
    gemm(ws + oH2, nullptr, ws + oM2, ws + oH3, b_red2, ws + oQ3,
         128, 640, 256, 256, 640, 640, 32768, 163840, 81920, 16, 1, 256, 1);
    // 12. h4 = relu(h3 @ W_down2 + b_down2), single-pass
    gemm(ws + oH3, nullptr, W_down2, ws + oH4, b_down2, nullptr,
         2048, 512, 640, 640, 512, 512, 0, 0, 0, 1, 1, 640, 1);
    // 13-14. h5 = relu(h4 viewed (16x65536) @ W_flat + b_flat), split-K 128
    gemm(ws + oH4, nullptr, W_flat, ws + oPartF, nullptr, nullptr,
         16, 512, 65536, 65536, 512, 512, 0, 0, 0, 1, 128, 512, 0);
    reduce_splitk<<<dim3(32), blk, 0, stream>>>(ws + oPartF, ws + oH5, b_flat,
                                                nullptr, 8192, 512, 1, 128, 1);
    // 15-17. dense chain
    gemm(ws + oH5, nullptr, W_d1, ws + oH6, b_d1, nullptr,
         16, 512, 512, 512, 512, 512, 0, 0, 0, 1, 1, 512, 1);
    gemm(ws + oH6, nullptr, W_d2, ws + oH7, b_d2, nullptr,
         16, 512, 512, 512, 512, 512, 0, 0, 0, 1, 1, 512, 1);
    gemm(ws + oH7, nullptr, W_d3, ws + oH8, b_d3, nullptr,
         16, 512, 512, 512, 512, 512, 0, 0, 0, 1, 1, 512, 1);
    // 18. out  = (h6+h8) @ W_p1 + (2*b_p1 + b_p2)
    gemm(ws + oH6, ws + oH8, W_p1, out, ws + oBC, nullptr,
         16, 32000, 512, 512, 32000, 32000, 0, 0, 0, 1, 1, 512, 0);
    // 19. out += h7 @ W_p2
    gemm(ws + oH7, nullptr, W_p2, out, nullptr, out,
         16, 32000, 512, 512, 32000, 32000, 0, 0, 0, 1, 1, 512, 0);
}